// Round 4
// baseline (446.510 us; speedup 1.0000x reference)
//
#include <hip/hip_runtime.h>
#include <stdint.h>

// R10: qkv_gemm ported to 256x256 (BK=64) 8-wave phase-split schedule.
//   - 512 thr / 8 waves (2M x 4N), per-wave C = 128x64 (acc[8][4]).
//   - LDS 128 KB: 2 dbuf x (A 256x64 + B 256x64) bf16, PROVEN zero-conflict
//     chunk-XOR layout (slot = chunk ^ (row&7)) kept from gemm_core.
//   - 4 phases per K-tile: (mg0,kk0)(mg1,kk0)(mg0,kk1)(mg1,kk1), 16 MFMA each,
//     raw s_barrier + lgkmcnt(0) + setprio around each MFMA cluster (T3/T5).
//   - T14 issue-early: ALL next-tile stages (8 gl2lds) issued at phase 1;
//     single late vmcnt(0) at phase 4 (~600cy after issue -> near-free drain).
//   - XCD-chunked swizzle: 384 blocks = 48/XCD, A-panels (2MB) L2-resident.
//   R9 post-mortem: qkv at exactly the m97 ceiling (MfmaUtil 38.7, 873 TF);
//   barrier-drain structure was the limiter, not BW (26% HBM) or banks (0).
// attn_k (R9 LDS-shared), proj_gemm, wtrans, cvt, rope unchanged.

typedef unsigned short u16;
typedef unsigned int u32;
typedef __attribute__((ext_vector_type(8))) short bf16x8;
typedef __attribute__((ext_vector_type(4))) float f32x4;

#define SEQ 2048
#define DM 2048
#define NH 16
#define HD 128
#define SM_SCALE 0.08838834764831845f
#define K2LOG 0.12751743f   // SM_SCALE * log2(e)

__device__ __forceinline__ u16 f2bf(float f) {
  union { float f; uint32_t u; } v; v.f = f;
  uint32_t u = v.u + 0x7fffu + ((v.u >> 16) & 1u);   // RNE
  return (u16)(u >> 16);
}
__device__ __forceinline__ float bf2f(u16 h) {
  union { uint32_t u; float f; } v; v.u = ((uint32_t)h) << 16; return v.f;
}
__device__ __forceinline__ u32 pack2(float a, float b) {
  return (u32)f2bf(a) | ((u32)f2bf(b) << 16);
}
__device__ __forceinline__ u32 pack2_trunc(float a, float b) {   // RTZ: P in [0,1]
  union { float f; u32 u; } x, y; x.f = a; y.f = b;
  return (x.u >> 16) | (y.u & 0xFFFF0000u);
}

// async global->LDS, 16B per lane; LDS dest = wave-uniform base + lane*16 (HW)
__device__ __forceinline__ void gl2lds16(const void* g, void* l) {
  __builtin_amdgcn_global_load_lds(
      (const __attribute__((address_space(1))) uint32_t*)g,
      (__attribute__((address_space(3))) uint32_t*)l, 16, 0, 0);
}

// ---------------- elementwise fp32 -> bf16 of x ----------------
__global__ __launch_bounds__(256) void cvt_x(const float* __restrict__ x, u16* __restrict__ xb) {
  int i = blockIdx.x * 256 + threadIdx.x;
  float4 v = ((const float4*)x)[i];
  uint2 r;
  r.x = pack2(v.x, v.y);
  r.y = pack2(v.z, v.w);
  ((uint2*)xb)[i] = r;
}

// ---------------- W (K,N) fp32 -> Wt (N,K) bf16, tiled transpose ----------------
__global__ __launch_bounds__(256) void wtrans(const float* __restrict__ w0, const float* __restrict__ w1,
                                              const float* __restrict__ w2, const float* __restrict__ w3,
                                              u16* __restrict__ dst) {
  const float* W = blockIdx.z == 0 ? w0 : blockIdx.z == 1 ? w1 : blockIdx.z == 2 ? w2 : w3;
  u16* D = dst + (size_t)blockIdx.z * DM * DM;
  int k0 = blockIdx.x * 32, n0 = blockIdx.y * 32;
  __shared__ u16 t[32][33];
  int tx = threadIdx.x, ty = threadIdx.y;   // (32,8)
#pragma unroll
  for (int i = 0; i < 32; i += 8)
    t[ty + i][tx] = f2bf(W[(size_t)(k0 + ty + i) * DM + n0 + tx]);
  __syncthreads();
#pragma unroll
  for (int i = 0; i < 32; i += 8)
    D[(size_t)(n0 + ty + i) * DM + k0 + tx] = t[tx][ty + i];
}

// ---------------- 128x128 (BK=64) bf16 MFMA GEMM core (proj only) ----------------
__device__ __forceinline__ void gemm_core(const u16* __restrict__ A, const u16* __restrict__ Bt,
                                          int m0, int n0, u16* As, u16* Bs, f32x4 acc[4][4]) {
  int tid = threadIdx.x, lane = tid & 63;
  int l15 = lane & 15, quad = lane >> 4;
  int wave = tid >> 6;
  int wm = (wave >> 1) * 64, wn = (wave & 1) * 64;
  for (int k0 = 0; k0 < DM; k0 += 64) {
#pragma unroll
    for (int i = 0; i < 4; ++i) {
      int s = i * 256 + tid;
      int row = s >> 3, c = (s & 7) ^ (row & 7);
      gl2lds16(&A[(size_t)(m0 + row) * DM + k0 + c * 8], &As[(s & ~63) * 8]);
      gl2lds16(&Bt[(size_t)(n0 + row) * DM + k0 + c * 8], &Bs[(s & ~63) * 8]);
    }
    __syncthreads();
#pragma unroll
    for (int kk = 0; kk < 2; ++kk) {
      bf16x8 af[4], bfr[4];
#pragma unroll
      for (int mt = 0; mt < 4; ++mt) {
        int row = wm + mt * 16 + l15;
        int c = (kk * 4 + quad) ^ (row & 7);
        af[mt] = *(const bf16x8*)&As[row * 64 + c * 8];
      }
#pragma unroll
      for (int nt = 0; nt < 4; ++nt) {
        int row = wn + nt * 16 + l15;
        int c = (kk * 4 + quad) ^ (row & 7);
        bfr[nt] = *(const bf16x8*)&Bs[row * 64 + c * 8];
      }
#pragma unroll
      for (int mt = 0; mt < 4; ++mt)
#pragma unroll
        for (int nt = 0; nt < 4; ++nt)
          acc[mt][nt] = __builtin_amdgcn_mfma_f32_16x16x32_bf16(af[mt], bfr[nt], acc[mt][nt], 0, 0, 0);
    }
    __syncthreads();
  }
}

// ---------------- QKV: 256x256 tile, 8-wave, phase-split pipelined ----------------
// Grid: 384 blocks (1-D). swz = (bid&7)*48 + bid>>3 -> XCD gets 48 consecutive jobs
// (2 M-panels x 24 N-panels: A-panels stay L2-resident per XCD).
// z = n-panel>>3 selects Wq/Wk/Wv; z==2 writes V transposed into Vt.
__global__ __launch_bounds__(512, 2) void qkv_gemm8(const u16* __restrict__ X, const u16* __restrict__ Wt,
                                                    u16* __restrict__ Qo, u16* __restrict__ Ko,
                                                    u16* __restrict__ Vto) {
  __shared__ u16 As[2][256 * 64];   // 64 KB
  __shared__ u16 Bs[2][256 * 64];   // 64 KB
  int tid = threadIdx.x, lane = tid & 63;
  int l15 = lane & 15, quad = lane >> 4;
  int w = tid >> 6, wm = w >> 2, wn = w & 3;   // 2M x 4N
  int bid = blockIdx.x;
  int swz = (bid & 7) * 48 + (bid >> 3);
  int by = swz / 24, bx = swz % 24;
  int z = bx >> 3;
  int n0 = (bx & 7) * 256;
  int m0 = by * 256;
  const u16* Bt = Wt + (size_t)z * DM * DM;

  // stage half h (rows h*128..+127) of a K-tile (k-offset kt) into L.
  // dest linear (DMA), source chunk inverse-swizzled: slot c of row r holds chunk c^(r&7).
  auto SH = [&](const u16* S, int rb, int kt, u16* L, int h) {
#pragma unroll
    for (int i = 0; i < 2; ++i) {
      int s = i * 512 + tid;           // 0..1023
      int r = s >> 3, c = (s & 7) ^ (r & 7);
      gl2lds16(&S[(size_t)(rb + h * 128 + r) * DM + kt + c * 8],
               &L[h * 128 * 64 + (s & ~63) * 8]);
    }
  };

  f32x4 acc[8][4] = {};
  bf16x8 a0[4], a1[4], bb[4][2];

  auto LDA = [&](bf16x8* dst, int mg, int kk, const u16* Ac) {
#pragma unroll
    for (int mi = 0; mi < 4; ++mi) {
      int row = wm * 128 + (mg * 4 + mi) * 16 + l15;
      dst[mi] = *(const bf16x8*)&Ac[row * 64 + (((kk * 4 + quad) ^ (row & 7)) * 8)];
    }
  };
  auto LDB = [&](int kk, const u16* Bc) {
#pragma unroll
    for (int ni = 0; ni < 4; ++ni) {
      int row = wn * 64 + ni * 16 + l15;
      bb[ni][kk] = *(const bf16x8*)&Bc[row * 64 + (((kk * 4 + quad) ^ (row & 7)) * 8)];
    }
  };
  auto MM = [&](bf16x8* af, int mg, int kk) {
    __builtin_amdgcn_s_setprio(1);
#pragma unroll
    for (int mi = 0; mi < 4; ++mi)
#pragma unroll
      for (int ni = 0; ni < 4; ++ni)
        acc[mg * 4 + mi][ni] =
            __builtin_amdgcn_mfma_f32_16x16x32_bf16(af[mi], bb[ni][kk], acc[mg * 4 + mi][ni], 0, 0, 0);
    __builtin_amdgcn_s_setprio(0);
  };

  // prologue: tile 0 -> buf 0, full drain (once)
  SH(X, m0, 0, (u16*)As[0], 0); SH(X, m0, 0, (u16*)As[0], 1);
  SH(Bt, n0, 0, (u16*)Bs[0], 0); SH(Bt, n0, 0, (u16*)Bs[0], 1);
  asm volatile("s_waitcnt vmcnt(0)" ::: "memory");
  __builtin_amdgcn_s_barrier();

  for (int t = 0; t < 32; ++t) {
    const u16* Ac = As[t & 1];
    const u16* Bc = Bs[t & 1];
    // ---- phase 1: reads (A mg0 kk0 + B kk0) ; issue-early stage of tile t+1 ----
    LDA(a0, 0, 0, Ac);
    LDB(0, Bc);
    if (t < 31) {
      int kt1 = (t + 1) * 64;
      u16* An = (u16*)As[(t & 1) ^ 1];
      u16* Bn = (u16*)Bs[(t & 1) ^ 1];
      SH(X, m0, kt1, An, 0); SH(X, m0, kt1, An, 1);
      SH(Bt, n0, kt1, Bn, 0); SH(Bt, n0, kt1, Bn, 1);
    }
    asm volatile("" ::: "memory");
    __builtin_amdgcn_s_barrier();
    asm volatile("s_waitcnt lgkmcnt(0)" ::: "memory");
    MM(a0, 0, 0);
    __builtin_amdgcn_s_barrier();
    // ---- phase 2: A mg1 kk0 ----
    LDA(a1, 1, 0, Ac);
    asm volatile("" ::: "memory");
    __builtin_amdgcn_s_barrier();
    asm volatile("s_waitcnt lgkmcnt(0)" ::: "memory");
    MM(a1, 1, 0);
    __builtin_amdgcn_s_barrier();
    // ---- phase 3: A mg0 kk1 + B kk1 ----
    LDA(a0, 0, 1, Ac);
    LDB(1, Bc);
    asm volatile("" ::: "memory");
    __builtin_amdgcn_s_barrier();
    asm volatile("s_waitcnt lgkmcnt(0)" ::: "memory");
    MM(a0, 0, 1);
    __builtin_amdgcn_s_barrier();
    // ---- phase 4: A mg1 kk1 ; late drain of next-tile stages ----
    LDA(a1, 1, 1, Ac);
    asm volatile("" ::: "memory");
    __builtin_amdgcn_s_barrier();
    asm volatile("s_waitcnt lgkmcnt(0)" ::: "memory");
    MM(a1, 1, 1);
    asm volatile("s_waitcnt vmcnt(0)" ::: "memory");   // tile t+1 resident (issued ~3.5 phases ago)
    __builtin_amdgcn_s_barrier();
  }

  // epilogue
  int wmbase = m0 + wm * 128;
  int wnbase = n0 + wn * 64;
  if (z == 2) {
#pragma unroll
    for (int mi = 0; mi < 8; ++mi)
#pragma unroll
      for (int ni = 0; ni < 4; ++ni) {
        int tok = wmbase + mi * 16 + quad * 4;
        int d = wnbase + ni * 16 + l15;
        int h = d >> 7, dh = d & 127;
        int b = tok >> 11, sx = tok & (SEQ - 1);
        u16* dp = &Vto[((size_t)(b * NH + h) * HD + dh) * SEQ + sx];
        *(u32*)&dp[0] = pack2(acc[mi][ni][0], acc[mi][ni][1]);
        *(u32*)&dp[2] = pack2(acc[mi][ni][2], acc[mi][ni][3]);
      }
  } else {
    u16* C = (z == 0) ? Qo : Ko;
#pragma unroll
    for (int mi = 0; mi < 8; ++mi)
#pragma unroll
      for (int ni = 0; ni < 4; ++ni)
#pragma unroll
        for (int r = 0; r < 4; ++r)
          C[(size_t)(wmbase + mi * 16 + quad * 4 + r) * DM + wnbase + ni * 16 + l15]
              = f2bf(acc[mi][ni][r]);
  }
}

__global__ __launch_bounds__(256) void proj_gemm(const u16* __restrict__ A, const u16* __restrict__ Wt,
                                                 float* __restrict__ C) {
  __shared__ u16 As[128 * 64];
  __shared__ u16 Bs[128 * 64];
  int n0 = blockIdx.x * 128, m0 = blockIdx.y * 128;
  f32x4 acc[4][4] = {};
  gemm_core(A, Wt, m0, n0, As, Bs, acc);
  int lane = threadIdx.x & 63, wave = threadIdx.x >> 6;
  int l15 = lane & 15, quad = lane >> 4;
  int wm = (wave >> 1) * 64, wn = (wave & 1) * 64;
#pragma unroll
  for (int mt = 0; mt < 4; ++mt)
#pragma unroll
    for (int nt = 0; nt < 4; ++nt)
#pragma unroll
      for (int r = 0; r < 4; ++r)
        C[(size_t)(m0 + wm + mt * 16 + quad * 4 + r) * DM + n0 + wn + nt * 16 + l15] = acc[mt][nt][r];
}

// ---------------- RoPE in-place on Q (y=0) and K (y=1), fast sincos ----------------
__global__ __launch_bounds__(256) void rope_k(u16* __restrict__ Q, u16* __restrict__ K,
                                              const int* __restrict__ pos) {
  uint32_t idx = blockIdx.x * 256 + threadIdx.x;
  int i = idx & 63;
  int h = (idx >> 6) & 15;
  int s = (idx >> 10) & 2047;
  int b = idx >> 21;
  u16* P = (blockIdx.y == 0) ? Q : K;
  int p = pos[b * SEQ + s];
  float inv_rev = exp2f(fmaf((float)i, -0.20762051f, -2.6514961f));
  float pf = (float)p;
  float hi = pf * inv_rev;
  float err = fmaf(pf, inv_rev, -hi);
  float r = (hi - truncf(hi)) + err;
  float ang = r * 6.2831853f;
  float sn = __sinf(ang), cs = __cosf(ang);
  size_t base = ((size_t)(b * SEQ + s)) * DM + h * HD;
  float x1 = bf2f(P[base + i]), x2 = bf2f(P[base + 64 + i]);
  P[base + i] = f2bf(x1 * cs - x2 * sn);
  P[base + 64 + i] = f2bf(x2 * cs + x1 * sn);
}

// ---------------- Flash attention: LDS-shared K/V, 4 stripes of one (b,h) per block --------
__global__ __launch_bounds__(256, 2) void attn_k(const u16* __restrict__ Q, const u16* __restrict__ K,
                                                 const u16* __restrict__ Vt, const int* __restrict__ pos,
                                                 u16* __restrict__ AO) {
  __shared__ u16 Ks[2][64 * 128];    // 16 KB per buffer
  __shared__ u16 Vs[2][128 * 64];    // 16 KB per buffer
  int tid = threadIdx.x, lane = tid & 63, wave = tid >> 6;
  int bx = blockIdx.x;
  int bh = bx & 31;
  int g4 = bx >> 5;                      // 0..15
  int g = (bh & 1) ? (15 - g4) : g4;     // parity complement: heavy+light adjacency
  int b = bh >> 4, h = bh & 15;
  int stripe = 4 * g + wave;             // 0..63
  int l15 = lane & 15, quad = lane >> 4;
  const int* posb = pos + b * SEQ;
  int qbase = stripe * 32;
  const u16* Kg = &K[(size_t)(b * SEQ) * DM + h * HD];
  const u16* Vg = &Vt[(size_t)(b * NH + h) * HD * SEQ];

  bf16x8 qf[2][4];
#pragma unroll
  for (int qi = 0; qi < 2; ++qi)
#pragma unroll
    for (int kk = 0; kk < 4; ++kk)
      qf[qi][kk] = *(const bf16x8*)&Q[(size_t)(b * SEQ + qbase + qi * 16 + l15) * DM
                                      + h * HD + kk * 32 + quad * 8];

  auto ub = [&](int v) {
    int c = 0;
#pragma unroll
    for (int st = 1024; st; st >>= 1)
      if (posb[c + st - 1] <= v) c += st;
    if (c == 2047 && posb[2047] <= v) c = 2048;
    return c;
  };
  int cnt[2];
  cnt[0] = ub(posb[qbase + l15]);
  cnt[1] = ub(posb[qbase + 16 + l15]);
  int cnt_min = ub(posb[qbase]);
  int cnt_max = ub(posb[qbase + 31]);
  int ntile = (cnt_max + 63) >> 6;
  int cnt_blk = ub(posb[(4 * g + 3) * 32 + 31]);
  int ntile_blk = (cnt_blk + 63) >> 6;

  auto STAGE = [&](int j0, int bufi) {
#pragma unroll
    for (int i = 0; i < 4; ++i) {
      int s = i * 256 + tid;
      int rk = s >> 4, ck = (s & 15) ^ (rk & 15);
      gl2lds16(&Kg[(size_t)(j0 + rk) * DM + ck * 8], &Ks[bufi][(s & ~63) * 8]);
      int rv = s >> 3, cv = (s & 7) ^ (rv & 7);
      gl2lds16(&Vg[(size_t)rv * SEQ + j0 + cv * 8], &Vs[bufi][(s & ~63) * 8]);
    }
  };

  STAGE(0, 0);
  __syncthreads();

  float m_i[2] = {-1.0e30f, -1.0e30f}, l_i[2] = {0.0f, 0.0f};
  f32x4 oacc[2][8] = {};

  int base0 = l15 + ((quad & 1) << 5);
  bool hi_sel = (quad >> 1) != 0;

  for (int j = 0; j < ntile_blk; ++j) {
    int cur = j & 1;
    if (j + 1 < ntile_blk) STAGE((j + 1) * 64, cur ^ 1);

    if (j < ntile) {
      int j0 = j * 64;
      f32x4 sacc[2][4] = {};
#pragma unroll
      for (int kt = 0; kt < 4; ++kt) {
        bf16x8 kfa[4];
#pragma unroll
        for (int kk = 0; kk < 4; ++kk) {
          int cs = (kk * 4 + quad) ^ l15;
          kfa[kk] = *(const bf16x8*)&Ks[cur][((kt * 16 + l15) * 16 + cs) * 8];
        }
#pragma unroll
        for (int qi = 0; qi < 2; ++qi)
#pragma unroll
          for (int kk = 0; kk < 4; ++kk)
            sacc[qi][kt] = __builtin_amdgcn_mfma_f32_16x16x32_bf16(kfa[kk], qf[qi][kk], sacc[qi][kt], 0, 0, 0);
      }

      bool need_mask = (j0 + 64 > cnt_min);
      u32 pb[2][4][2];
#pragma unroll
      for (int qi = 0; qi < 2; ++qi) {
        if (need_mask) {
          int rel = cnt[qi] - j0;
#pragma unroll
          for (int kt = 0; kt < 4; ++kt)
#pragma unroll
            for (int r = 0; r < 4; ++r)
              if (kt * 16 + quad * 4 + r >= rel) sacc[qi][kt][r] = -1.0e30f;
        }
        float mx = fmaxf(fmaxf(sacc[qi][0][0], sacc[qi][0][1]), fmaxf(sacc[qi][0][2], sacc[qi][0][3]));
#pragma unroll
        for (int kt = 1; kt < 4; ++kt)
          mx = fmaxf(mx, fmaxf(fmaxf(sacc[qi][kt][0], sacc[qi][kt][1]),
                               fmaxf(sacc[qi][kt][2], sacc[qi][kt][3])));
        mx = fmaxf(mx, __shfl_xor(mx, 16));
        mx = fmaxf(mx, __shfl_xor(mx, 32));
        float mold = m_i[qi];
        float mn = fmaxf(mold, mx);
        if (__any(mn > mold)) {
          float al = exp2f((mold - mn) * K2LOG);
          l_i[qi] *= al;
#pragma unroll
          for (int dt = 0; dt < 8; ++dt) oacc[qi][dt] *= al;
          m_i[qi] = mn;
        }
        float nc = -m_i[qi] * K2LOG;
        float rs = 0.0f;
#pragma unroll
        for (int kt = 0; kt < 4; ++kt) {
          float p0 = exp2f(fmaf(sacc[qi][kt][0], K2LOG, nc));
          float p1 = exp2f(fmaf(sacc[qi][kt][1], K2LOG, nc));
          float p2 = exp2f(fmaf(sacc[qi][kt][2], K2LOG, nc));
          float p3 = exp2f(fmaf(sacc[qi][kt][3], K2LOG, nc));
          rs += (p0 + p1) + (p2 + p3);
          pb[qi][kt][0] = pack2_trunc(p0, p1);
          pb[qi][kt][1] = pack2_trunc(p2, p3);
        }
        rs += __shfl_xor(rs, 16);
        rs += __shfl_xor(rs, 32);
        l_i[qi] += rs;
      }

#pragma unroll
      for (int kk2 = 0; kk2 < 2; ++kk2) {
        bf16x8 vf[8];
#pragma unroll
        for (int dt = 0; dt < 8; ++dt) {
          int cs = (kk2 * 4 + quad) ^ (l15 & 7);
          vf[dt] = *(const bf16x8*)&Vs[cur][((dt * 16 + l15) * 8 + cs) * 8];
        }
#pragma unroll
        for (int qi = 0; qi < 2; ++qi) {
          u32 wv[4];
#pragma unroll
          for (int wd = 0; wd < 4; ++wd) {
            int src = base0 + ((wd >> 1) << 4);
            u32 va = __shfl(pb[qi][kk2 * 2 + 0][wd & 1], src);
            u32 vb = __shfl(pb[qi][kk2 * 2 + 1][wd & 1], src);
            wv[wd] = hi_sel ? vb : va;
          }
          union { bf16x8 v; u32 u[4]; } pt;
          pt.u[0] = wv[0]; pt.u[1] = wv[1]; pt.u[2] = wv[2]; pt.u[3] = wv[3];
#pragma unroll
          for (int dt = 0; dt < 8; ++dt)
            oacc[qi][dt] = __builtin_amdgcn_mfma_f32_16x16x32_bf16(vf[dt], pt.v, oacc[qi][dt], 0, 0, 0);
        }
      }
    }
    __syncthreads();
  }

#pragma unroll
  for (int qi = 0; qi < 2; ++qi) {
    float inv = 1.0f / l_i[qi];
    u16* aop = &AO[(size_t)(b * SEQ + qbase + qi * 16 + l15) * DM + h * HD];
#pragma unroll
    for (int dt = 0; dt < 8; ++dt) {
      int col = dt * 16 + quad * 4;
      *(u32*)&aop[col]     = pack2(oacc[qi][dt][0] * inv, oacc[qi][dt][1] * inv);
      *(u32*)&aop[col + 2] = pack2(oacc[qi][dt][2] * inv, oacc[qi][dt][3] * inv);
    }
  }
}

extern "C" void kernel_launch(void* const* d_in, const int* in_sizes, int n_in,
                              void* d_out, int out_size, void* d_ws, size_t ws_size,
                              hipStream_t stream) {
  const float* x  = (const float*)d_in[0];
  const float* Wq = (const float*)d_in[1];
  const float* Wk = (const float*)d_in[2];
  const float* Wv = (const float*)d_in[3];
  const float* Wo = (const float*)d_in[4];
  const int*  pos = (const int*)d_in[5];
  float* out = (float*)d_out;

  u16* ws  = (u16*)d_ws;
  u16* xb  = ws;
  u16* wt  = xb  + (size_t)4096 * 2048;
  u16* qb  = wt  + (size_t)4 * 2048 * 2048;
  u16* kb  = qb  + (size_t)4096 * 2048;
  u16* vtb = kb  + (size_t)4096 * 2048;
  u16* aob = vtb + (size_t)4096 * 2048;

  cvt_x<<<8192, 256, 0, stream>>>(x, xb);
  wtrans<<<dim3(64, 64, 4), dim3(32, 8), 0, stream>>>(Wq, Wk, Wv, Wo, wt);
  qkv_gemm8<<<dim3(384), 512, 0, stream>>>(xb, wt, qb, kb, vtb);
  rope_k<<<dim3(16384, 2), 256, 0, stream>>>(qb, kb, pos);
  attn_k<<<dim3(512), 256, 0, stream>>>(qb, kb, vtb, pos, aob);
  proj_gemm<<<dim3(16, 32), 256, 0, stream>>>(aob, wt + (size_t)3 * 2048 * 2048, out);
}

// Round 5
// 435.472 us; speedup vs baseline: 1.0253x; 1.0253x over previous
//
#include <hip/hip_runtime.h>
#include <stdint.h>

// R11: revert qkv to verified R9 m97-structure (R10 8-phase port regressed:
//   MfmaUtil 27.9 vs 38.7, lockstep barrier alternation, vmcnt(0) stalls).
//   One safe change on top of R9: gemm_core K-loop -> DOUBLE-BUFFERED LDS with a
//   SINGLE __syncthreads per K-step (T3-minimum recipe). Hazard proof:
//   iter t DMAs buf^1 while reading buf[cur]; buf^1's readers (iter t-1) drained
//   ds_reads before iter t-1's barrier (lgkmcnt(0) emitted with s_barrier), and
//   the remaining barrier's implicit vmcnt(0) publishes tile t+1. 64KB LDS ->
//   2 blocks/CU. Shared by qkv_gemm and proj_gemm. attn_k already uses this
//   structure (R9, verified). Everything else byte-identical to R9.

typedef unsigned short u16;
typedef unsigned int u32;
typedef __attribute__((ext_vector_type(8))) short bf16x8;
typedef __attribute__((ext_vector_type(4))) float f32x4;

#define SEQ 2048
#define DM 2048
#define NH 16
#define HD 128
#define SM_SCALE 0.08838834764831845f
#define K2LOG 0.12751743f   // SM_SCALE * log2(e)

__device__ __forceinline__ u16 f2bf(float f) {
  union { float f; uint32_t u; } v; v.f = f;
  uint32_t u = v.u + 0x7fffu + ((v.u >> 16) & 1u);   // RNE
  return (u16)(u >> 16);
}
__device__ __forceinline__ float bf2f(u16 h) {
  union { uint32_t u; float f; } v; v.u = ((uint32_t)h) << 16; return v.f;
}
__device__ __forceinline__ u32 pack2(float a, float b) {
  return (u32)f2bf(a) | ((u32)f2bf(b) << 16);
}
__device__ __forceinline__ u32 pack2_trunc(float a, float b) {   // RTZ: P in [0,1]
  union { float f; u32 u; } x, y; x.f = a; y.f = b;
  return (x.u >> 16) | (y.u & 0xFFFF0000u);
}

// async global->LDS, 16B per lane; LDS dest = wave-uniform base + lane*16 (HW)
__device__ __forceinline__ void gl2lds16(const void* g, void* l) {
  __builtin_amdgcn_global_load_lds(
      (const __attribute__((address_space(1))) uint32_t*)g,
      (__attribute__((address_space(3))) uint32_t*)l, 16, 0, 0);
}

// ---------------- elementwise fp32 -> bf16 of x ----------------
__global__ __launch_bounds__(256) void cvt_x(const float* __restrict__ x, u16* __restrict__ xb) {
  int i = blockIdx.x * 256 + threadIdx.x;
  float4 v = ((const float4*)x)[i];
  uint2 r;
  r.x = pack2(v.x, v.y);
  r.y = pack2(v.z, v.w);
  ((uint2*)xb)[i] = r;
}

// ---------------- W (K,N) fp32 -> Wt (N,K) bf16, tiled transpose ----------------
__global__ __launch_bounds__(256) void wtrans(const float* __restrict__ w0, const float* __restrict__ w1,
                                              const float* __restrict__ w2, const float* __restrict__ w3,
                                              u16* __restrict__ dst) {
  const float* W = blockIdx.z == 0 ? w0 : blockIdx.z == 1 ? w1 : blockIdx.z == 2 ? w2 : w3;
  u16* D = dst + (size_t)blockIdx.z * DM * DM;
  int k0 = blockIdx.x * 32, n0 = blockIdx.y * 32;
  __shared__ u16 t[32][33];
  int tx = threadIdx.x, ty = threadIdx.y;   // (32,8)
#pragma unroll
  for (int i = 0; i < 32; i += 8)
    t[ty + i][tx] = f2bf(W[(size_t)(k0 + ty + i) * DM + n0 + tx]);
  __syncthreads();
#pragma unroll
  for (int i = 0; i < 32; i += 8)
    D[(size_t)(n0 + ty + i) * DM + k0 + tx] = t[tx][ty + i];
}

// ------- 128x128 (BK=64) bf16 MFMA GEMM core: dbuf LDS, ONE barrier per K-step -------
__device__ __forceinline__ void gemm_core(const u16* __restrict__ A, const u16* __restrict__ Bt,
                                          int m0, int n0, u16 (*As)[128 * 64], u16 (*Bs)[128 * 64],
                                          f32x4 acc[4][4]) {
  int tid = threadIdx.x, lane = tid & 63;
  int l15 = lane & 15, quad = lane >> 4;
  int wave = tid >> 6;
  int wm = (wave >> 1) * 64, wn = (wave & 1) * 64;

  auto STAGE = [&](int k0, int bufi) {
#pragma unroll
    for (int i = 0; i < 4; ++i) {
      int s = i * 256 + tid;
      int row = s >> 3, c = (s & 7) ^ (row & 7);
      gl2lds16(&A[(size_t)(m0 + row) * DM + k0 + c * 8], &As[bufi][(s & ~63) * 8]);
      gl2lds16(&Bt[(size_t)(n0 + row) * DM + k0 + c * 8], &Bs[bufi][(s & ~63) * 8]);
    }
  };

  STAGE(0, 0);
  __syncthreads();   // implicit vmcnt(0): tile 0 resident

  for (int kt = 0; kt < 32; ++kt) {
    int cur = kt & 1;
    if (kt < 31) STAGE((kt + 1) * 64, cur ^ 1);   // DMA next tile under compute
    const u16* Ac = As[cur];
    const u16* Bc = Bs[cur];
#pragma unroll
    for (int kk = 0; kk < 2; ++kk) {
      bf16x8 af[4], bfr[4];
#pragma unroll
      for (int mt = 0; mt < 4; ++mt) {
        int row = wm + mt * 16 + l15;
        int c = (kk * 4 + quad) ^ (row & 7);
        af[mt] = *(const bf16x8*)&Ac[row * 64 + c * 8];
      }
#pragma unroll
      for (int nt = 0; nt < 4; ++nt) {
        int row = wn + nt * 16 + l15;
        int c = (kk * 4 + quad) ^ (row & 7);
        bfr[nt] = *(const bf16x8*)&Bc[row * 64 + c * 8];
      }
#pragma unroll
      for (int mt = 0; mt < 4; ++mt)
#pragma unroll
        for (int nt = 0; nt < 4; ++nt)
          acc[mt][nt] = __builtin_amdgcn_mfma_f32_16x16x32_bf16(af[mt], bfr[nt], acc[mt][nt], 0, 0, 0);
    }
    __syncthreads();   // publishes tile kt+1 (vmcnt0) + closes reads of tile kt
  }
}

// z=0 -> Q, z=1 -> K (row-major bf16), z=2 -> V stored TRANSPOSED into Vt (b,h,d,s)
__global__ __launch_bounds__(256) void qkv_gemm(const u16* __restrict__ X, const u16* __restrict__ Wt,
                                                u16* __restrict__ Qo, u16* __restrict__ Ko,
                                                u16* __restrict__ Vto) {
  __shared__ u16 As[2][128 * 64];
  __shared__ u16 Bs[2][128 * 64];
  const u16* Bt = Wt + (size_t)blockIdx.z * DM * DM;
  int n0 = blockIdx.x * 128, m0 = blockIdx.y * 128;
  f32x4 acc[4][4] = {};
  gemm_core(X, Bt, m0, n0, As, Bs, acc);
  int lane = threadIdx.x & 63, wave = threadIdx.x >> 6;
  int l15 = lane & 15, quad = lane >> 4;
  int wm = (wave >> 1) * 64, wn = (wave & 1) * 64;
  if (blockIdx.z == 2) {
    int h = n0 >> 7;
#pragma unroll
    for (int mt = 0; mt < 4; ++mt)
#pragma unroll
      for (int nt = 0; nt < 4; ++nt) {
        int tok = m0 + wm + mt * 16 + quad * 4;
        int d = wn + nt * 16 + l15;
        int b = tok >> 11, sx = tok & (SEQ - 1);
        u16* dp = &Vto[((size_t)(b * NH + h) * HD + d) * SEQ + sx];
        *(u32*)&dp[0] = pack2(acc[mt][nt][0], acc[mt][nt][1]);
        *(u32*)&dp[2] = pack2(acc[mt][nt][2], acc[mt][nt][3]);
      }
  } else {
    u16* C = blockIdx.z == 0 ? Qo : Ko;
#pragma unroll
    for (int mt = 0; mt < 4; ++mt)
#pragma unroll
      for (int nt = 0; nt < 4; ++nt)
#pragma unroll
        for (int r = 0; r < 4; ++r)
          C[(size_t)(m0 + wm + mt * 16 + quad * 4 + r) * DM + n0 + wn + nt * 16 + l15]
              = f2bf(acc[mt][nt][r]);
  }
}

__global__ __launch_bounds__(256) void proj_gemm(const u16* __restrict__ A, const u16* __restrict__ Wt,
                                                 float* __restrict__ C) {
  __shared__ u16 As[2][128 * 64];
  __shared__ u16 Bs[2][128 * 64];
  int n0 = blockIdx.x * 128, m0 = blockIdx.y * 128;
  f32x4 acc[4][4] = {};
  gemm_core(A, Wt, m0, n0, As, Bs, acc);
  int lane = threadIdx.x & 63, wave = threadIdx.x >> 6;
  int l15 = lane & 15, quad = lane >> 4;
  int wm = (wave >> 1) * 64, wn = (wave & 1) * 64;
#pragma unroll
  for (int mt = 0; mt < 4; ++mt)
#pragma unroll
    for (int nt = 0; nt < 4; ++nt)
#pragma unroll
      for (int r = 0; r < 4; ++r)
        C[(size_t)(m0 + wm + mt * 16 + quad * 4 + r) * DM + n0 + wn + nt * 16 + l15] = acc[mt][nt][r];
}

// ---------------- RoPE in-place on Q (y=0) and K (y=1), fast sincos ----------------
__global__ __launch_bounds__(256) void rope_k(u16* __restrict__ Q, u16* __restrict__ K,
                                              const int* __restrict__ pos) {
  uint32_t idx = blockIdx.x * 256 + threadIdx.x;
  int i = idx & 63;
  int h = (idx >> 6) & 15;
  int s = (idx >> 10) & 2047;
  int b = idx >> 21;
  u16* P = (blockIdx.y == 0) ? Q : K;
  int p = pos[b * SEQ + s];
  float inv_rev = exp2f(fmaf((float)i, -0.20762051f, -2.6514961f));
  float pf = (float)p;
  float hi = pf * inv_rev;
  float err = fmaf(pf, inv_rev, -hi);
  float r = (hi - truncf(hi)) + err;
  float ang = r * 6.2831853f;
  float sn = __sinf(ang), cs = __cosf(ang);
  size_t base = ((size_t)(b * SEQ + s)) * DM + h * HD;
  float x1 = bf2f(P[base + i]), x2 = bf2f(P[base + 64 + i]);
  P[base + i] = f2bf(x1 * cs - x2 * sn);
  P[base + 64 + i] = f2bf(x2 * cs + x1 * sn);
}

// ---------------- Flash attention: LDS-shared K/V, 4 stripes of one (b,h) per block --------
__global__ __launch_bounds__(256, 2) void attn_k(const u16* __restrict__ Q, const u16* __restrict__ K,
                                                 const u16* __restrict__ Vt, const int* __restrict__ pos,
                                                 u16* __restrict__ AO) {
  __shared__ u16 Ks[2][64 * 128];    // 16 KB per buffer
  __shared__ u16 Vs[2][128 * 64];    // 16 KB per buffer
  int tid = threadIdx.x, lane = tid & 63, wave = tid >> 6;
  int bx = blockIdx.x;
  int bh = bx & 31;
  int g4 = bx >> 5;                      // 0..15
  int g = (bh & 1) ? (15 - g4) : g4;     // parity complement: heavy+light adjacency
  int b = bh >> 4, h = bh & 15;
  int stripe = 4 * g + wave;             // 0..63
  int l15 = lane & 15, quad = lane >> 4;
  const int* posb = pos + b * SEQ;
  int qbase = stripe * 32;
  const u16* Kg = &K[(size_t)(b * SEQ) * DM + h * HD];
  const u16* Vg = &Vt[(size_t)(b * NH + h) * HD * SEQ];

  bf16x8 qf[2][4];
#pragma unroll
  for (int qi = 0; qi < 2; ++qi)
#pragma unroll
    for (int kk = 0; kk < 4; ++kk)
      qf[qi][kk] = *(const bf16x8*)&Q[(size_t)(b * SEQ + qbase + qi * 16 + l15) * DM
                                      + h * HD + kk * 32 + quad * 8];

  auto ub = [&](int v) {
    int c = 0;
#pragma unroll
    for (int st = 1024; st; st >>= 1)
      if (posb[c + st - 1] <= v) c += st;
    if (c == 2047 && posb[2047] <= v) c = 2048;
    return c;
  };
  int cnt[2];
  cnt[0] = ub(posb[qbase + l15]);
  cnt[1] = ub(posb[qbase + 16 + l15]);
  int cnt_min = ub(posb[qbase]);
  int cnt_max = ub(posb[qbase + 31]);
  int ntile = (cnt_max + 63) >> 6;
  int cnt_blk = ub(posb[(4 * g + 3) * 32 + 31]);
  int ntile_blk = (cnt_blk + 63) >> 6;

  auto STAGE = [&](int j0, int bufi) {
#pragma unroll
    for (int i = 0; i < 4; ++i) {
      int s = i * 256 + tid;
      int rk = s >> 4, ck = (s & 15) ^ (rk & 15);
      gl2lds16(&Kg[(size_t)(j0 + rk) * DM + ck * 8], &Ks[bufi][(s & ~63) * 8]);
      int rv = s >> 3, cv = (s & 7) ^ (rv & 7);
      gl2lds16(&Vg[(size_t)rv * SEQ + j0 + cv * 8], &Vs[bufi][(s & ~63) * 8]);
    }
  };

  STAGE(0, 0);
  __syncthreads();

  float m_i[2] = {-1.0e30f, -1.0e30f}, l_i[2] = {0.0f, 0.0f};
  f32x4 oacc[2][8] = {};

  int base0 = l15 + ((quad & 1) << 5);
  bool hi_sel = (quad >> 1) != 0;

  for (int j = 0; j < ntile_blk; ++j) {
    int cur = j & 1;
    if (j + 1 < ntile_blk) STAGE((j + 1) * 64, cur ^ 1);

    if (j < ntile) {
      int j0 = j * 64;
      f32x4 sacc[2][4] = {};
#pragma unroll
      for (int kt = 0; kt < 4; ++kt) {
        bf16x8 kfa[4];
#pragma unroll
        for (int kk = 0; kk < 4; ++kk) {
          int cs = (kk * 4 + quad) ^ l15;
          kfa[kk] = *(const bf16x8*)&Ks[cur][((kt * 16 + l15) * 16 + cs) * 8];
        }
#pragma unroll
        for (int qi = 0; qi < 2; ++qi)
#pragma unroll
          for (int kk = 0; kk < 4; ++kk)
            sacc[qi][kt] = __builtin_amdgcn_mfma_f32_16x16x32_bf16(kfa[kk], qf[qi][kk], sacc[qi][kt], 0, 0, 0);
      }

      bool need_mask = (j0 + 64 > cnt_min);
      u32 pb[2][4][2];
#pragma unroll
      for (int qi = 0; qi < 2; ++qi) {
        if (need_mask) {
          int rel = cnt[qi] - j0;
#pragma unroll
          for (int kt = 0; kt < 4; ++kt)
#pragma unroll
            for (int r = 0; r < 4; ++r)
              if (kt * 16 + quad * 4 + r >= rel) sacc[qi][kt][r] = -1.0e30f;
        }
        float mx = fmaxf(fmaxf(sacc[qi][0][0], sacc[qi][0][1]), fmaxf(sacc[qi][0][2], sacc[qi][0][3]));
#pragma unroll
        for (int kt = 1; kt < 4; ++kt)
          mx = fmaxf(mx, fmaxf(fmaxf(sacc[qi][kt][0], sacc[qi][kt][1]),
                               fmaxf(sacc[qi][kt][2], sacc[qi][kt][3])));
        mx = fmaxf(mx, __shfl_xor(mx, 16));
        mx = fmaxf(mx, __shfl_xor(mx, 32));
        float mold = m_i[qi];
        float mn = fmaxf(mold, mx);
        if (__any(mn > mold)) {
          float al = exp2f((mold - mn) * K2LOG);
          l_i[qi] *= al;
#pragma unroll
          for (int dt = 0; dt < 8; ++dt) oacc[qi][dt] *= al;
          m_i[qi] = mn;
        }
        float nc = -m_i[qi] * K2LOG;
        float rs = 0.0f;
#pragma unroll
        for (int kt = 0; kt < 4; ++kt) {
          float p0 = exp2f(fmaf(sacc[qi][kt][0], K2LOG, nc));
          float p1 = exp2f(fmaf(sacc[qi][kt][1], K2LOG, nc));
          float p2 = exp2f(fmaf(sacc[qi][kt][2], K2LOG, nc));
          float p3 = exp2f(fmaf(sacc[qi][kt][3], K2LOG, nc));
          rs += (p0 + p1) + (p2 + p3);
          pb[qi][kt][0] = pack2_trunc(p0, p1);
          pb[qi][kt][1] = pack2_trunc(p2, p3);
        }
        rs += __shfl_xor(rs, 16);
        rs += __shfl_xor(rs, 32);
        l_i[qi] += rs;
      }

#pragma unroll
      for (int kk2 = 0; kk2 < 2; ++kk2) {
        bf16x8 vf[8];
#pragma unroll
        for (int dt = 0; dt < 8; ++dt) {
          int cs = (kk2 * 4 + quad) ^ (l15 & 7);
          vf[dt] = *(const bf16x8*)&Vs[cur][((dt * 16 + l15) * 8 + cs) * 8];
        }
#pragma unroll
        for (int qi = 0; qi < 2; ++qi) {
          u32 wv[4];
#pragma unroll
          for (int wd = 0; wd < 4; ++wd) {
            int src = base0 + ((wd >> 1) << 4);
            u32 va = __shfl(pb[qi][kk2 * 2 + 0][wd & 1], src);
            u32 vb = __shfl(pb[qi][kk2 * 2 + 1][wd & 1], src);
            wv[wd] = hi_sel ? vb : va;
          }
          union { bf16x8 v; u32 u[4]; } pt;
          pt.u[0] = wv[0]; pt.u[1] = wv[1]; pt.u[2] = wv[2]; pt.u[3] = wv[3];
#pragma unroll
          for (int dt = 0; dt < 8; ++dt)
            oacc[qi][dt] = __builtin_amdgcn_mfma_f32_16x16x32_bf16(vf[dt], pt.v, oacc[qi][dt], 0, 0, 0);
        }
      }
    }
    __syncthreads();
  }

#pragma unroll
  for (int qi = 0; qi < 2; ++qi) {
    float inv = 1.0f / l_i[qi];
    u16* aop = &AO[(size_t)(b * SEQ + qbase + qi * 16 + l15) * DM + h * HD];
#pragma unroll
    for (int dt = 0; dt < 8; ++dt) {
      int col = dt * 16 + quad * 4;
      *(u32*)&aop[col]     = pack2(oacc[qi][dt][0] * inv, oacc[qi][dt][1] * inv);
      *(u32*)&aop[col + 2] = pack2(oacc[qi][dt][2] * inv, oacc[qi][dt][3] * inv);
    }
  }
}

extern "C" void kernel_launch(void* const* d_in, const int* in_sizes, int n_in,
                              void* d_out, int out_size, void* d_ws, size_t ws_size,
                              hipStream_t stream) {
  const float* x  = (const float*)d_in[0];
  const float* Wq = (const float*)d_in[1];
  const float* Wk = (const float*)d_in[2];
  const float* Wv = (const float*)d_in[3];
  const float* Wo = (const float*)d_in[4];
  const int*  pos = (const int*)d_in[5];
  float* out = (float*)d_out;

  u16* ws  = (u16*)d_ws;
  u16* xb  = ws;
  u16* wt  = xb  + (size_t)4096 * 2048;
  u16* qb  = wt  + (size_t)4 * 2048 * 2048;
  u16* kb  = qb  + (size_t)4096 * 2048;
  u16* vtb = kb  + (size_t)4096 * 2048;
  u16* aob = vtb + (size_t)4096 * 2048;

  cvt_x<<<8192, 256, 0, stream>>>(x, xb);
  wtrans<<<dim3(64, 64, 4), dim3(32, 8), 0, stream>>>(Wq, Wk, Wv, Wo, wt);
  qkv_gemm<<<dim3(16, 32, 3), 256, 0, stream>>>(xb, wt, qb, kb, vtb);
  rope_k<<<dim3(16384, 2), 256, 0, stream>>>(qb, kb, pos);
  attn_k<<<dim3(512), 256, 0, stream>>>(qb, kb, vtb, pos, aob);
  proj_gemm<<<dim3(16, 32), 256, 0, stream>>>(aob, wt + (size_t)3 * 2048 * 2048, out);
}